// Round 8
// baseline (933.229 us; speedup 1.0000x reference)
//
#include <hip/hip_runtime.h>

// fastmax linear attention (causal, p=1): SINGLE-PASS chunked scan with
// decoupled lookback (rocPRIM/CUB pattern) + bf16 MFMA matmuls.
// b=2, h=8, n=8192, d=32 -> bh=16, chunks of C=64 rows, 128 chunks per bh.
// Aggregate per chunk: KV (32x32, permuted-col layout) + Ksum(32) + Vsum(32)
//  = 1088 fp32.  Numerator matmuls in bf16 MFMA; denominator entirely fp32.
// Ticket (atomicAdd) assigns virtual block id = start order -> lookback only
// waits on blocks that already started => deadlock-free without relying on
// dispatch order.  Coherence: __threadfence (L2 writeback) + release flag /
// agent-scope acquire flag (L2 invalidate) around the payload.

#define D      32
#define C      64
#define NCHUNK 128
#define BH     16
#define NBLK   (BH * NCHUNK)   // 2048
#define STATE  1088

typedef __attribute__((ext_vector_type(8))) short bf16x8;
typedef __attribute__((ext_vector_type(4))) float f32x4;
typedef __attribute__((ext_vector_type(4))) unsigned short u16x4;

__device__ __forceinline__ unsigned short f2bf(float x) {
  union { float f; unsigned u; } c; c.f = x;
  unsigned r = (c.u + 0x7FFFu + ((c.u >> 16) & 1u)) >> 16;   // RNE
  return (unsigned short)r;
}

// MFMA output col n = original col (n<16 ? 2n : 2(n-16)+1); element with
// original col e stages at row n(e) = (e&1) ? 16+(e>>1) : (e>>1)
__device__ __forceinline__ int permcol(int e) {
  return (e & 1) ? (16 + (e >> 1)) : (e >> 1);
}

// ---------------------------------------------------------------------------
__global__ __launch_bounds__(256) void zero_flags_kernel(int* __restrict__ flags) {
  int i = blockIdx.x * 256 + threadIdx.x;
  if (i < NBLK + 1) flags[i] = 0;     // flags[NBLK] = ticket counter
}

// ---------------------------------------------------------------------------
__global__ __launch_bounds__(256) void fused_kernel(
    const float* __restrict__ q, const float* __restrict__ k,
    const float* __restrict__ v, float* __restrict__ agg,
    float* __restrict__ incl, int* __restrict__ flags,
    float* __restrict__ out) {
  __shared__ __align__(16) unsigned short qbf[C * 40];    // [i][dd]
  __shared__ __align__(16) unsigned short kbf[C * 40];    // [j][dd]
  __shared__ __align__(16) unsigned short vTbf[D * 72];   // [n][j] permuted cols
  __shared__ __align__(16) unsigned short kvTbf[D * 40];  // [n][dd] permuted cols
  __shared__ __align__(16) unsigned short uTK[C * 72];    // union: kT then Tbf
  __shared__ __align__(16) float q_s[C * 36];             // fp32 q rows
  __shared__ __align__(16) float kc_s[C * 36];            // fp32 k -> local cumsum
  __shared__ __align__(16) float aggLDS[STATE];
  __shared__ __align__(16) float4 kcolp[32];              // per-wave col partials
  __shared__ __align__(16) float4 vcolp[32];
  __shared__ __align__(16) float gtot[8 * 32];
  __shared__ __align__(16) float kpre_s[D], vpre_s[D];
  __shared__ __align__(16) float invdiv_s[C], dploc_s[C];
  __shared__ int bcast;

  unsigned short* kT  = uTK;          // [dd][j], natural cols (A-rows = d1)
  unsigned short* Tbf = uTK;          // [i][j], lives after kT is dead

  int t = threadIdx.x;

  // ---- ticket: virtual block id = start order -----------------------------
  if (t == 0) bcast = atomicAdd(&flags[NBLK], 1);
  __syncthreads();
  int vblk = bcast;
  int c    = vblk & 127;
  int fb   = vblk - c;                // bh * 128
  __syncthreads();                    // bcast reused by lookback later

  size_t off = (size_t)vblk * (C * D);
  const float4* qp4 = (const float4*)q + (size_t)vblk * 512;
  const float4* kp4 = (const float4*)k + (size_t)vblk * 512;
  const float4* vp4 = (const float4*)v + (size_t)vblk * 512;

  // ---- stage q,k,v (once) -------------------------------------------------
  int j0 = t >> 3;
  int cb = (t & 7) * 4;
  float4 qA = qp4[t], qB = qp4[t + 256];
  float4 kA = kp4[t], kB = kp4[t + 256];
  float4 vA = vp4[t], vB = vp4[t + 256];

  *(float4*)&q_s[j0 * 36 + cb]         = qA;
  *(float4*)&q_s[(j0 + 32) * 36 + cb]  = qB;
  *(float4*)&kc_s[j0 * 36 + cb]        = kA;
  *(float4*)&kc_s[(j0 + 32) * 36 + cb] = kB;
  *(u16x4*)&qbf[j0 * 40 + cb] =
      (u16x4){f2bf(qA.x), f2bf(qA.y), f2bf(qA.z), f2bf(qA.w)};
  *(u16x4*)&qbf[(j0 + 32) * 40 + cb] =
      (u16x4){f2bf(qB.x), f2bf(qB.y), f2bf(qB.z), f2bf(qB.w)};
  *(u16x4*)&kbf[j0 * 40 + cb] =
      (u16x4){f2bf(kA.x), f2bf(kA.y), f2bf(kA.z), f2bf(kA.w)};
  *(u16x4*)&kbf[(j0 + 32) * 40 + cb] =
      (u16x4){f2bf(kB.x), f2bf(kB.y), f2bf(kB.z), f2bf(kB.w)};
  {
    const float* ka = &kA.x; const float* kb = &kB.x;
    const float* va = &vA.x; const float* vb = &vB.x;
#pragma unroll
    for (int cc = 0; cc < 4; ++cc) {
      int n = permcol(cb + cc);
      vTbf[n * 72 + j0]           = f2bf(va[cc]);
      vTbf[n * 72 + j0 + 32]      = f2bf(vb[cc]);
      kT[(cb + cc) * 72 + j0]      = f2bf(ka[cc]);   // natural col order
      kT[(cb + cc) * 72 + j0 + 32] = f2bf(kb[cc]);
    }
  }
  // fp32 column partial sums via shuffle (for exact ksum/vsum)
  {
    float4 pk = make_float4(kA.x + kB.x, kA.y + kB.y, kA.z + kB.z, kA.w + kB.w);
    float4 pv = make_float4(vA.x + vB.x, vA.y + vB.y, vA.z + vB.z, vA.w + vB.w);
#pragma unroll
    for (int o = 32; o >= 8; o >>= 1) {
      pk.x += __shfl_down(pk.x, o); pk.y += __shfl_down(pk.y, o);
      pk.z += __shfl_down(pk.z, o); pk.w += __shfl_down(pk.w, o);
      pv.x += __shfl_down(pv.x, o); pv.y += __shfl_down(pv.y, o);
      pv.z += __shfl_down(pv.z, o); pv.w += __shfl_down(pv.w, o);
    }
    if ((t & 63) < 8) {
      kcolp[(t >> 6) * 8 + (t & 7)] = pk;
      vcolp[(t >> 6) * 8 + (t & 7)] = pv;
    }
  }
  __syncthreads();

  int lane = t & 63, w = t >> 6;
  int m16 = lane & 15, quad = lane >> 4;

  // ---- local aggregate: KV = K^T.V (MFMA, permuted cols) + ksum/vsum ------
  int mb = w >> 1, nb = w & 1;
  f32x4 acc = {0.f, 0.f, 0.f, 0.f};
#pragma unroll
  for (int kb2 = 0; kb2 < 2; ++kb2) {
    bf16x8 a = *(const bf16x8*)&kT[(16 * mb + m16) * 72 + kb2 * 32 + quad * 8];
    bf16x8 b = *(const bf16x8*)&vTbf[(16 * nb + m16) * 72 + kb2 * 32 + quad * 8];
    acc = __builtin_amdgcn_mfma_f32_16x16x32_bf16(a, b, acc, 0, 0, 0);
  }
  int idx0 = (16 * nb + m16) * 32 + 16 * mb + quad * 4;   // [n][d1], d1 consec
#pragma unroll
  for (int reg = 0; reg < 4; ++reg) aggLDS[idx0 + reg] = acc[reg];

  float csum = 0.f;
  if (t < 64) {
    int e = t & 31;
    const float* colF = (t < 32) ? (const float*)kcolp : (const float*)vcolp;
#pragma unroll
    for (int ww = 0; ww < 4; ++ww) csum += colF[ww * 32 + e];
    aggLDS[1024 + t] = csum;
  }

  // ---- publish ------------------------------------------------------------
  if (c > 0 && c < 127) {             // aggregate for lookback consumers
    float* ap = agg + (size_t)vblk * STATE;
#pragma unroll
    for (int reg = 0; reg < 4; ++reg) ap[idx0 + reg] = acc[reg];
    if (t < 64) ap[1024 + t] = csum;
  } else if (c == 0) {                // inclusive prefix == own aggregate
    float* ip = incl + (size_t)vblk * STATE;
#pragma unroll
    for (int reg = 0; reg < 4; ++reg) ip[idx0 + reg] = acc[reg];
    if (t < 64) ip[1024 + t] = csum;
  }
  __threadfence();
  __syncthreads();                    // also: last use of kT before Tbf reuse
  if (t == 0 && c < 127)
    __hip_atomic_store(&flags[vblk], (c == 0) ? 2 : 1,
                       __ATOMIC_RELEASE, __HIP_MEMORY_SCOPE_AGENT);

  // ---- prefix-independent work: Tbf zero + scan phase a -------------------
  for (int z = t; z < (C * 72) / 8; z += 256)
    ((uint4*)Tbf)[z] = make_uint4(0, 0, 0, 0);
  int rg = t >> 5;
  int e  = t & 31;
  float vals[8];
  {
    float run = 0.f;
#pragma unroll
    for (int r = 0; r < 8; ++r) {
      vals[r] = kc_s[(rg * 8 + r) * 36 + e];
      run += vals[r];
    }
    gtot[rg * 32 + e] = run;
  }
  __syncthreads();

  // ---- S = Q.K^T tiles -> Tbf (bf16, masked);  local k-cumsum (part b) ----
  const bf16x8 aQ = *(const bf16x8*)&qbf[(16 * w + m16) * 40 + quad * 8];
  for (int jb = 0; jb <= w; ++jb) {
    bf16x8 bK = *(const bf16x8*)&kbf[(16 * jb + m16) * 40 + quad * 8];
    f32x4 cS = {0.f, 0.f, 0.f, 0.f};
    cS = __builtin_amdgcn_mfma_f32_16x16x32_bf16(aQ, bK, cS, 0, 0, 0);
    int jcol = 16 * jb + m16;
#pragma unroll
    for (int reg = 0; reg < 4; ++reg) {
      int i = 16 * w + quad * 4 + reg;
      float tv = (jcol <= i) ? (1.f + cS[reg]) : 0.f;
      Tbf[i * 72 + jcol] = f2bf(tv);
    }
  }
  {
    float offv = 0.f;                 // local cumsum only (no prefix yet)
    for (int g = 0; g < rg; ++g) offv += gtot[g * 32 + e];
    float cacc = offv;
#pragma unroll
    for (int r = 0; r < 8; ++r) {
      cacc += vals[r];
      kc_s[(rg * 8 + r) * 36 + e] = cacc;
    }
  }
  __syncthreads();

  // dploc_i = q_i . local_cumsum_i   (fp32)
  if (t < 64) {
    int i = t;
    float dp = 0.f;
#pragma unroll
    for (int d4 = 0; d4 < 8; ++d4) {
      float4 qv = *(const float4*)&q_s[i * 36 + 4 * d4];
      float4 kc = *(const float4*)&kc_s[i * 36 + 4 * d4];
      dp += qv.x * kc.x + qv.y * kc.y + qv.z * kc.z + qv.w * kc.w;
    }
    dploc_s[i] = dp;
  }

  // ---- decoupled lookback -------------------------------------------------
  float r0 = 0.f, r1 = 0.f, r2 = 0.f, r3 = 0.f, r4 = 0.f;
  int p = c - 1;
  while (p >= 0) {
    if (t == 0) {
      int f;
      do {
        f = __hip_atomic_load(&flags[fb + p], __ATOMIC_ACQUIRE,
                              __HIP_MEMORY_SCOPE_AGENT);
        if (f == 0) __builtin_amdgcn_s_sleep(1);
      } while (f == 0);
      bcast = f;
    }
    __syncthreads();
    int f = bcast;
    const float* src = ((f == 2) ? incl : agg) + (size_t)(fb + p) * STATE;
    r0 += src[t];       r1 += src[t + 256];
    r2 += src[t + 512]; r3 += src[t + 768];
    if (t < 64) r4 += src[t + 1024];
    __syncthreads();                  // protect bcast before next overwrite
    if (f == 2) break;
    --p;
  }

  // ---- prefix -> LDS; publish inclusive prefix ----------------------------
  {
    float rr[4] = {r0, r1, r2, r3};
#pragma unroll
    for (int r = 0; r < 4; ++r) {
      int idx = t + 256 * r;
      kvTbf[(idx >> 5) * 40 + (idx & 31)] = f2bf(rr[r]);
    }
    if (t < 32)      kpre_s[t]      = r4;
    else if (t < 64) vpre_s[t - 32] = r4;
    if (c > 0 && c < 127) {
      float* ip = incl + (size_t)vblk * STATE;
      ip[t]       = r0 + aggLDS[t];
      ip[t + 256] = r1 + aggLDS[t + 256];
      ip[t + 512] = r2 + aggLDS[t + 512];
      ip[t + 768] = r3 + aggLDS[t + 768];
      if (t < 64) ip[t + 1024] = r4 + aggLDS[t + 1024];
      __threadfence();
    }
  }
  __syncthreads();
  if (t == 0 && c > 0 && c < 127)
    __hip_atomic_store(&flags[vblk], 2, __ATOMIC_RELEASE,
                       __HIP_MEMORY_SCOPE_AGENT);

  // ---- denominator (fp32) + O MFMAs ---------------------------------------
  if (t < 64) {
    int i = t;
    float dp = 0.f;
#pragma unroll
    for (int d4 = 0; d4 < 8; ++d4) {
      float4 qv = *(const float4*)&q_s[i * 36 + 4 * d4];
      float4 kp = *(const float4*)&kpre_s[4 * d4];
      dp += qv.x * kp.x + qv.y * kp.y + qv.z * kp.z + qv.w * kp.w;
    }
    invdiv_s[i] = 1.f / ((float)(c * C + i + 1) + dploc_s[i] + dp);
  }
  f32x4 o0 = {0.f, 0.f, 0.f, 0.f}, o1 = {0.f, 0.f, 0.f, 0.f};
  {
    bf16x8 b0 = *(const bf16x8*)&kvTbf[(m16)      * 40 + quad * 8];
    bf16x8 b1 = *(const bf16x8*)&kvTbf[(16 + m16) * 40 + quad * 8];
    o0 = __builtin_amdgcn_mfma_f32_16x16x32_bf16(aQ, b0, o0, 0, 0, 0);
    o1 = __builtin_amdgcn_mfma_f32_16x16x32_bf16(aQ, b1, o1, 0, 0, 0);
  }
  int kbcnt = (w >= 2) ? 2 : 1;       // T zero past column 16w+15
  for (int kb2 = 0; kb2 < kbcnt; ++kb2) {
    bf16x8 aT = *(const bf16x8*)&Tbf[(16 * w + m16) * 72 + kb2 * 32 + quad * 8];
    bf16x8 b0 = *(const bf16x8*)&vTbf[(m16)      * 72 + kb2 * 32 + quad * 8];
    bf16x8 b1 = *(const bf16x8*)&vTbf[(16 + m16) * 72 + kb2 * 32 + quad * 8];
    o0 = __builtin_amdgcn_mfma_f32_16x16x32_bf16(aT, b0, o0, 0, 0, 0);
    o1 = __builtin_amdgcn_mfma_f32_16x16x32_bf16(aT, b1, o1, 0, 0, 0);
  }
  __syncthreads();

  // ---- epilogue: columns 2*m16, 2*m16+1 -> float2 stores ------------------
  int e0 = 2 * m16;
#pragma unroll
  for (int reg = 0; reg < 4; ++reg) {
    int i = 16 * w + quad * 4 + reg;
    float id = invdiv_s[i];
    float2 o;
    o.x = (vpre_s[e0]     + o0[reg]) * id;
    o.y = (vpre_s[e0 + 1] + o1[reg]) * id;
    *(float2*)&out[off + (size_t)i * D + e0] = o;
  }
}

// ---------------------------------------------------------------------------
extern "C" void kernel_launch(void* const* d_in, const int* in_sizes, int n_in,
                              void* d_out, int out_size, void* d_ws, size_t ws_size,
                              hipStream_t stream) {
  const float* q = (const float*)d_in[0];
  const float* k = (const float*)d_in[1];
  const float* v = (const float*)d_in[2];
  float* out  = (float*)d_out;
  float* agg  = (float*)d_ws;                               // 8.9 MB
  float* incl = agg + (size_t)NBLK * STATE;                 // 8.9 MB
  int*  flags = (int*)(incl + (size_t)NBLK * STATE);        // 2049 ints

  zero_flags_kernel<<<(NBLK + 1 + 255) / 256, 256, 0, stream>>>(flags);
  fused_kernel<<<NBLK, 256, 0, stream>>>(q, k, v, agg, incl, flags, out);
}

// Round 9
// 111.044 us; speedup vs baseline: 8.4041x; 8.4041x over previous
//
#include <hip/hip_runtime.h>

// fastmax linear attention (causal, p=1): chunked scan + bf16 MFMA matmuls.
// b=2, h=8, n=8192, d=32 -> bh=16, chunks of C=64 rows, 128 chunks per bh.
// State: KV (32x32 [d1][d2]) + Ksum(32) + Vsum(32) = 1088 fp32 per chunk.
// R9 structure (two kernels):
//  A) state_scan: 256 blocks = 16 bh x 16 groups of 8 chunks.  Each block
//     walks its 8 chunks sequentially (prefix in REGISTERS, depth 8 -- the
//     anti-R8), writing exclusive-within-group prefixes + inclusive group
//     totals.  Next chunk's k,v prefetched into registers during MFMA.
//  B) output: prefix = states[chunk] + sum of totals of earlier groups
//     (<=15 L2-resident 4.35KB vectors, 4-way ILP).  Numerator bf16 MFMA;
//     denominator entirely fp32 (tiny values!).

#define D      32
#define C      64
#define NCHUNK 128
#define GSIZE  8
#define NGROUP 16
#define BH     16
#define NBLK   (BH * NCHUNK)
#define STATE  1088

typedef __attribute__((ext_vector_type(8))) short bf16x8;
typedef __attribute__((ext_vector_type(4))) float f32x4;
typedef __attribute__((ext_vector_type(4))) unsigned short u16x4;

__device__ __forceinline__ unsigned short f2bf(float x) {
  union { float f; unsigned u; } c; c.f = x;
  unsigned r = (c.u + 0x7FFFu + ((c.u >> 16) & 1u)) >> 16;   // RNE
  return (unsigned short)r;
}

// MFMA output col n = original col (n<16 ? 2n : 2(n-16)+1); element with
// original col e stages at row n(e) = (e&1) ? 16+(e>>1) : (e>>1)
__device__ __forceinline__ int permcol(int e) {
  return (e & 1) ? (16 + (e >> 1)) : (e >> 1);
}

__device__ __forceinline__ float4 add4(float4 a, float4 b) {
  return make_float4(a.x + b.x, a.y + b.y, a.z + b.z, a.w + b.w);
}

// ---------------------------------------------------------------------------
// Kernel A: per-group sequential chunk-state scan.  grid = BH*NGROUP = 256.
// ---------------------------------------------------------------------------
__global__ __launch_bounds__(256) void state_scan_kernel(
    const float* __restrict__ k, const float* __restrict__ v,
    float* __restrict__ states, float* __restrict__ totals) {
  int blk = blockIdx.x;                  // bh*NGROUP + g
  int c0  = blk * GSIZE;                 // first global chunk index
  const float4* kp = (const float4*)k + (size_t)c0 * 512;
  const float4* vp = (const float4*)v + (size_t)c0 * 512;

  __shared__ __align__(16) unsigned short kT[D * 72];   // [e][j]
  __shared__ __align__(16) unsigned short vT[D * 72];   // [e][j]
  __shared__ __align__(16) float4 psK[256];             // per-thread col partials
  __shared__ __align__(16) float4 psV[256];

  int t  = threadIdx.x;
  int j0 = t >> 3;
  int cb = (t & 7) * 4;
  int lane = t & 63, w = t >> 6;
  int m16 = lane & 15, quad = lane >> 4;
  int mb = w >> 1, nb = w & 1;
  int d1b = 16 * mb + quad * 4;
  int d2  = 16 * nb + m16;

  float pref[4] = {0.f, 0.f, 0.f, 0.f};  // running KV prefix (this thread's 4)
  float tailpref = 0.f;                  // running ksum/vsum prefix (t<64)

  float4 kA = kp[t], kB = kp[t + 256];   // preload chunk 0
  float4 vA = vp[t], vB = vp[t + 256];

  for (int ci = 0; ci < GSIZE; ++ci) {
    // stage current chunk
    {
      const float* ka = &kA.x; const float* kb = &kB.x;
      const float* va = &vA.x; const float* vb = &vB.x;
#pragma unroll
      for (int cc = 0; cc < 4; ++cc) {
        kT[(cb + cc) * 72 + j0]      = f2bf(ka[cc]);
        kT[(cb + cc) * 72 + j0 + 32] = f2bf(kb[cc]);
        vT[(cb + cc) * 72 + j0]      = f2bf(va[cc]);
        vT[(cb + cc) * 72 + j0 + 32] = f2bf(vb[cc]);
      }
      psK[t] = make_float4(kA.x + kB.x, kA.y + kB.y, kA.z + kB.z, kA.w + kB.w);
      psV[t] = make_float4(vA.x + vB.x, vA.y + vB.y, vA.z + vB.z, vA.w + vB.w);
    }
    __syncthreads();

    // prefetch next chunk while MFMA runs
    if (ci + 1 < GSIZE) {
      const float4* kn = kp + (size_t)(ci + 1) * 512;
      const float4* vn = vp + (size_t)(ci + 1) * 512;
      kA = kn[t]; kB = kn[t + 256];
      vA = vn[t]; vB = vn[t + 256];
    }

    // KV = K^T.V for this chunk (4 16x16 tiles across 4 waves)
    f32x4 acc = {0.f, 0.f, 0.f, 0.f};
#pragma unroll
    for (int kb2 = 0; kb2 < 2; ++kb2) {
      bf16x8 a = *(const bf16x8*)&kT[(16 * mb + m16) * 72 + kb2 * 32 + quad * 8];
      bf16x8 b = *(const bf16x8*)&vT[(16 * nb + m16) * 72 + kb2 * 32 + quad * 8];
      acc = __builtin_amdgcn_mfma_f32_16x16x32_bf16(a, b, acc, 0, 0, 0);
    }
    float csum = 0.f;
    if (t < 64) {
      int ee = t & 31;
      const float* ps = (t < 32) ? (const float*)psK : (const float*)psV;
#pragma unroll
      for (int m = 0; m < 32; ++m) csum += ps[ee + 32 * m];
    }

    // write EXCLUSIVE prefix, then fold in own aggregate
    float* stC = states + (size_t)(c0 + ci) * STATE;
#pragma unroll
    for (int reg = 0; reg < 4; ++reg) {
      stC[(d1b + reg) * 32 + d2] = pref[reg];
      pref[reg] += acc[reg];
    }
    if (t < 64) {
      stC[1024 + t] = tailpref;
      tailpref += csum;
    }
    __syncthreads();                    // protect kT/vT/psK before re-staging
  }

  // inclusive group total
  float* tp = totals + (size_t)blk * STATE;
#pragma unroll
  for (int reg = 0; reg < 4; ++reg) tp[(d1b + reg) * 32 + d2] = pref[reg];
  if (t < 64) tp[1024 + t] = tailpref;
}

// ---------------------------------------------------------------------------
// Kernel B: MFMA output kernel.  grid = BH*NCHUNK, 256 threads (4 waves).
// ---------------------------------------------------------------------------
__global__ __launch_bounds__(256) void output_kernel(
    const float* __restrict__ q, const float* __restrict__ k,
    const float* __restrict__ v, const float* __restrict__ states,
    const float* __restrict__ totals, float* __restrict__ out) {
  int blk = blockIdx.x;
  int c   = blk & 127;
  int bh  = blk >> 7;
  int g   = c >> 3;                    // group index (GSIZE=8)
  size_t off = (size_t)blk * (C * D);
  const float4* qp4 = (const float4*)q + (size_t)blk * 512;
  const float4* kp4 = (const float4*)k + (size_t)blk * 512;
  const float4* vp4 = (const float4*)v + (size_t)blk * 512;
  const float4* st4 = (const float4*)(states + (size_t)blk * STATE);
  const float4* tb4 = (const float4*)(totals + (size_t)(bh * NGROUP) * STATE);

  __shared__ __align__(16) unsigned short qbf[C * 40];    // [i][dd]
  __shared__ __align__(16) unsigned short kbf[C * 40];    // [j][dd]
  __shared__ __align__(16) unsigned short vTbf[D * 72];   // [n][j] permuted cols
  __shared__ __align__(16) unsigned short kvTbf[D * 40];  // [n][dd] permuted cols
  __shared__ __align__(16) unsigned short Tbf[C * 72];    // [i][j]
  __shared__ __align__(16) float q_s[C * 36];             // fp32 q rows
  __shared__ __align__(16) float kc_s[C * 36];            // fp32 k -> cumsum+kpre
  __shared__ __align__(16) float gtot[8 * 32];
  __shared__ __align__(16) float kpre_s[D], vpre_s[D], invdiv_s[C];

  int t  = threadIdx.x;
  int j0 = t >> 3;
  int cb = (t & 7) * 4;

  // ---- issue all global loads first ---------------------------------------
  float4 qA = qp4[t], qB = qp4[t + 256];
  float4 kA = kp4[t], kB = kp4[t + 256];
  float4 vA = vp4[t], vB = vp4[t + 256];
  float4 sv = st4[t];                          // within-group exclusive prefix
  float4 tail = make_float4(0.f, 0.f, 0.f, 0.f);
  if (t < 16) tail = st4[256 + t];             // kpre (8) + vpre (8)

  // add earlier groups' totals (L2-resident), 4-way ILP
  {
    float4 a0 = make_float4(0.f, 0.f, 0.f, 0.f), a1 = a0, a2 = a0, a3 = a0;
    int gp = 0;
    for (; gp + 4 <= g; gp += 4) {
      a0 = add4(a0, tb4[(size_t)(gp + 0) * 272 + t]);
      a1 = add4(a1, tb4[(size_t)(gp + 1) * 272 + t]);
      a2 = add4(a2, tb4[(size_t)(gp + 2) * 272 + t]);
      a3 = add4(a3, tb4[(size_t)(gp + 3) * 272 + t]);
    }
    for (; gp < g; ++gp) a0 = add4(a0, tb4[(size_t)gp * 272 + t]);
    sv = add4(sv, add4(add4(a0, a1), add4(a2, a3)));
    if (t < 16)
      for (int g2 = 0; g2 < g; ++g2)
        tail = add4(tail, tb4[(size_t)g2 * 272 + 256 + t]);
  }

  // zero Tbf while loads are in flight (masked region must read 0)
  for (int z = t; z < (C * 72) / 8; z += 256)
    ((uint4*)Tbf)[z] = make_uint4(0, 0, 0, 0);

  // ---- convert + stage ----------------------------------------------------
  *(float4*)&q_s[j0 * 36 + cb]         = qA;
  *(float4*)&q_s[(j0 + 32) * 36 + cb]  = qB;
  *(float4*)&kc_s[j0 * 36 + cb]        = kA;
  *(float4*)&kc_s[(j0 + 32) * 36 + cb] = kB;
  *(u16x4*)&qbf[j0 * 40 + cb] =
      (u16x4){f2bf(qA.x), f2bf(qA.y), f2bf(qA.z), f2bf(qA.w)};
  *(u16x4*)&qbf[(j0 + 32) * 40 + cb] =
      (u16x4){f2bf(qB.x), f2bf(qB.y), f2bf(qB.z), f2bf(qB.w)};
  *(u16x4*)&kbf[j0 * 40 + cb] =
      (u16x4){f2bf(kA.x), f2bf(kA.y), f2bf(kA.z), f2bf(kA.w)};
  *(u16x4*)&kbf[(j0 + 32) * 40 + cb] =
      (u16x4){f2bf(kB.x), f2bf(kB.y), f2bf(kB.z), f2bf(kB.w)};
  {
    const float* va = &vA.x; const float* vb = &vB.x;
    const float* sp = &sv.x;
#pragma unroll
    for (int cc = 0; cc < 4; ++cc) {
      int n = permcol(cb + cc);
      vTbf[n * 72 + j0]      = f2bf(va[cc]);
      vTbf[n * 72 + j0 + 32] = f2bf(vb[cc]);
      kvTbf[n * 40 + j0]     = f2bf(sp[cc]);   // KV[d1=j0][d2=cb+cc]
    }
  }
  if (t < 8)            ((float4*)kpre_s)[t]     = tail;
  else if (t < 16)      ((float4*)vpre_s)[t - 8] = tail;
  __syncthreads();

  int lane = t & 63, w = t >> 6;
  int m16 = lane & 15, quad = lane >> 4;

  // ---- part 1: S tiles -> Tbf;  scan phase a ------------------------------
  const bf16x8 aQ = *(const bf16x8*)&qbf[(16 * w + m16) * 40 + quad * 8];
  for (int jb = 0; jb <= w; ++jb) {
    bf16x8 bK = *(const bf16x8*)&kbf[(16 * jb + m16) * 40 + quad * 8];
    f32x4 cS = {0.f, 0.f, 0.f, 0.f};
    cS = __builtin_amdgcn_mfma_f32_16x16x32_bf16(aQ, bK, cS, 0, 0, 0);
    int jcol = 16 * jb + m16;
#pragma unroll
    for (int reg = 0; reg < 4; ++reg) {
      int i = 16 * w + quad * 4 + reg;
      float tv = (jcol <= i) ? (1.f + cS[reg]) : 0.f;
      Tbf[i * 72 + jcol] = f2bf(tv);
    }
  }
  int rg = t >> 5;                     // row-group 0..7
  int e  = t & 31;
  float vals[8];
  {
    float run = 0.f;
#pragma unroll
    for (int r = 0; r < 8; ++r) {
      vals[r] = kc_s[(rg * 8 + r) * 36 + e];
      run += vals[r];
    }
    gtot[rg * 32 + e] = run;
  }
  __syncthreads();

  // ---- part 2: apply group offsets + kpre, write k-cumsum -----------------
  {
    float offv = kpre_s[e];
    for (int g2 = 0; g2 < rg; ++g2) offv += gtot[g2 * 32 + e];
    float cacc = offv;
#pragma unroll
    for (int r = 0; r < 8; ++r) {
      cacc += vals[r];
      kc_s[(rg * 8 + r) * 36 + e] = cacc;   // kpre + cumsum_local(k)
    }
  }
  __syncthreads();

  // ---- part 3: fp32 den (wave 0) + O MFMAs (all waves) --------------------
  if (t < 64) {
    int i = t;
    float dp = 0.f;
#pragma unroll
    for (int d4 = 0; d4 < 8; ++d4) {
      float4 qv = *(const float4*)&q_s[i * 36 + 4 * d4];
      float4 kc = *(const float4*)&kc_s[i * 36 + 4 * d4];
      dp += qv.x * kc.x + qv.y * kc.y + qv.z * kc.z + qv.w * kc.w;
    }
    invdiv_s[i] = 1.f / ((float)(c * C + i + 1) + dp);
  }
  f32x4 o0 = {0.f, 0.f, 0.f, 0.f}, o1 = {0.f, 0.f, 0.f, 0.f};
  {
    bf16x8 b0 = *(const bf16x8*)&kvTbf[(m16)      * 40 + quad * 8];
    bf16x8 b1 = *(const bf16x8*)&kvTbf[(16 + m16) * 40 + quad * 8];
    o0 = __builtin_amdgcn_mfma_f32_16x16x32_bf16(aQ, b0, o0, 0, 0, 0);
    o1 = __builtin_amdgcn_mfma_f32_16x16x32_bf16(aQ, b1, o1, 0, 0, 0);
  }
  int kbcnt = (w >= 2) ? 2 : 1;        // T zero past column 16w+15
  for (int kb2 = 0; kb2 < kbcnt; ++kb2) {
    bf16x8 aT = *(const bf16x8*)&Tbf[(16 * w + m16) * 72 + kb2 * 32 + quad * 8];
    bf16x8 b0 = *(const bf16x8*)&vTbf[(m16)      * 72 + kb2 * 32 + quad * 8];
    bf16x8 b1 = *(const bf16x8*)&vTbf[(16 + m16) * 72 + kb2 * 32 + quad * 8];
    o0 = __builtin_amdgcn_mfma_f32_16x16x32_bf16(aT, b0, o0, 0, 0, 0);
    o1 = __builtin_amdgcn_mfma_f32_16x16x32_bf16(aT, b1, o1, 0, 0, 0);
  }
  __syncthreads();

  // ---- epilogue: columns 2*m16, 2*m16+1 -> float2 stores ------------------
  int e0 = 2 * m16;
#pragma unroll
  for (int reg = 0; reg < 4; ++reg) {
    int i = 16 * w + quad * 4 + reg;
    float id = invdiv_s[i];
    float2 o;
    o.x = (vpre_s[e0]     + o0[reg]) * id;
    o.y = (vpre_s[e0 + 1] + o1[reg]) * id;
    *(float2*)&out[off + (size_t)i * D + e0] = o;
  }
}

// ---------------------------------------------------------------------------
extern "C" void kernel_launch(void* const* d_in, const int* in_sizes, int n_in,
                              void* d_out, int out_size, void* d_ws, size_t ws_size,
                              hipStream_t stream) {
  const float* q = (const float*)d_in[0];
  const float* k = (const float*)d_in[1];
  const float* v = (const float*)d_in[2];
  float* out    = (float*)d_out;
  float* states = (float*)d_ws;                               // 8.9 MB
  float* totals = states + (size_t)NBLK * STATE;              // 1.1 MB

  state_scan_kernel<<<BH * NGROUP, 256, 0, stream>>>(k, v, states, totals);
  output_kernel<<<NBLK, 256, 0, stream>>>(q, k, v, states, totals, out);
}

// Round 10
// 103.800 us; speedup vs baseline: 8.9906x; 1.0698x over previous
//
#include <hip/hip_runtime.h>

// fastmax linear attention (causal, p=1): chunked scan + bf16 MFMA matmuls.
// b=2, h=8, n=8192, d=32 -> bh=16, chunks of C=64 rows, 128 chunks per bh.
// Three kernels:
//  1) state_scan: 256 blocks = 16 bh x 16 groups of 8 chunks.  Register
//     prefix scan (depth 8); writes per-chunk exclusive-within-group KV
//     prefix as bf16 in the MFMA staging layout ([n][d1], n = permuted d2)
//     + fp32 ksum/vsum tails; writes fp32 inclusive group totals.
//  2) totals_scan: exclusive scan of the 16 group totals per bh (in-place).
//  3) output: prefix = bf16 state + one fp32 totals vector.  Numerator in
//     bf16 MFMA; denominator entirely fp32 (tiny values!).

#define D      32
#define C      64
#define NCHUNK 128
#define GSIZE  8
#define NGROUP 16
#define BH     16
#define NBLK   (BH * NCHUNK)
#define STATE  1088            // totals: fp32 elems per vector (1024 KV + 64 tail)
#define STCH   1152            // states: ushorts per chunk (1024 KV + 64 f32 tail)

typedef __attribute__((ext_vector_type(8))) short bf16x8;
typedef __attribute__((ext_vector_type(4))) float f32x4;
typedef __attribute__((ext_vector_type(4))) unsigned short u16x4;

__device__ __forceinline__ unsigned short f2bf(float x) {
  union { float f; unsigned u; } c; c.f = x;
  unsigned r = (c.u + 0x7FFFu + ((c.u >> 16) & 1u)) >> 16;   // RNE
  return (unsigned short)r;
}
__device__ __forceinline__ float bf2f(unsigned short u) {
  union { unsigned u; float f; } c; c.u = ((unsigned)u) << 16;
  return c.f;
}
// MFMA output col n = original col (n<16 ? 2n : 2(n-16)+1); element with
// original col e stages at row n(e) = (e&1) ? 16+(e>>1) : (e>>1)
__device__ __forceinline__ int permcol(int e) {
  return (e & 1) ? (16 + (e >> 1)) : (e >> 1);
}
__device__ __forceinline__ float4 add4(float4 a, float4 b) {
  return make_float4(a.x + b.x, a.y + b.y, a.z + b.z, a.w + b.w);
}

// ---------------------------------------------------------------------------
// Kernel 1: per-group sequential chunk-state scan.  grid = BH*NGROUP = 256.
// ---------------------------------------------------------------------------
__global__ __launch_bounds__(256) void state_scan_kernel(
    const float* __restrict__ k, const float* __restrict__ v,
    unsigned short* __restrict__ states, float* __restrict__ totals) {
  int blk = blockIdx.x;                  // bh*NGROUP + g
  int c0  = blk * GSIZE;                 // first global chunk index
  const float4* kp = (const float4*)k + (size_t)c0 * 512;
  const float4* vp = (const float4*)v + (size_t)c0 * 512;

  __shared__ __align__(16) unsigned short kT[D * 72];   // [e][j]
  __shared__ __align__(16) unsigned short vT[D * 72];   // [e][j]
  __shared__ __align__(16) float4 psK[256];             // per-thread col partials
  __shared__ __align__(16) float4 psV[256];

  int t  = threadIdx.x;
  int j0 = t >> 3;
  int cb = (t & 7) * 4;
  int lane = t & 63, w = t >> 6;
  int m16 = lane & 15, quad = lane >> 4;
  int mb = w >> 1, nb = w & 1;
  int d1b = 16 * mb + quad * 4;
  int d2  = 16 * nb + m16;
  int n   = permcol(d2);                 // staging row for this thread's col

  float pref[4] = {0.f, 0.f, 0.f, 0.f};  // running KV prefix (this thread's 4)
  float tailpref = 0.f;                  // running ksum/vsum prefix (t<64)

  float4 kA = kp[t], kB = kp[t + 256];   // preload chunk 0
  float4 vA = vp[t], vB = vp[t + 256];

  for (int ci = 0; ci < GSIZE; ++ci) {
    // stage current chunk
    {
      const float* ka = &kA.x; const float* kb = &kB.x;
      const float* va = &vA.x; const float* vb = &vB.x;
#pragma unroll
      for (int cc = 0; cc < 4; ++cc) {
        kT[(cb + cc) * 72 + j0]      = f2bf(ka[cc]);
        kT[(cb + cc) * 72 + j0 + 32] = f2bf(kb[cc]);
        vT[(cb + cc) * 72 + j0]      = f2bf(va[cc]);
        vT[(cb + cc) * 72 + j0 + 32] = f2bf(vb[cc]);
      }
      psK[t] = make_float4(kA.x + kB.x, kA.y + kB.y, kA.z + kB.z, kA.w + kB.w);
      psV[t] = make_float4(vA.x + vB.x, vA.y + vB.y, vA.z + vB.z, vA.w + vB.w);
    }
    __syncthreads();

    // prefetch next chunk while MFMA runs
    if (ci + 1 < GSIZE) {
      const float4* kn = kp + (size_t)(ci + 1) * 512;
      const float4* vn = vp + (size_t)(ci + 1) * 512;
      kA = kn[t]; kB = kn[t + 256];
      vA = vn[t]; vB = vn[t + 256];
    }

    // KV = K^T.V for this chunk (4 16x16 tiles across 4 waves)
    f32x4 acc = {0.f, 0.f, 0.f, 0.f};
#pragma unroll
    for (int kb2 = 0; kb2 < 2; ++kb2) {
      bf16x8 a = *(const bf16x8*)&kT[(16 * mb + m16) * 72 + kb2 * 32 + quad * 8];
      bf16x8 b = *(const bf16x8*)&vT[(16 * nb + m16) * 72 + kb2 * 32 + quad * 8];
      acc = __builtin_amdgcn_mfma_f32_16x16x32_bf16(a, b, acc, 0, 0, 0);
    }
    float csum = 0.f;
    if (t < 64) {
      int ee = t & 31;
      const float* ps = (t < 32) ? (const float*)psK : (const float*)psV;
#pragma unroll
      for (int m = 0; m < 32; ++m) csum += ps[ee + 32 * m];
    }

    // write EXCLUSIVE prefix (KV as bf16, staging layout), fold own aggregate
    unsigned short* stC = states + (size_t)(c0 + ci) * STCH;
    *(u16x4*)&stC[n * 32 + d1b] =
        (u16x4){f2bf(pref[0]), f2bf(pref[1]), f2bf(pref[2]), f2bf(pref[3])};
#pragma unroll
    for (int reg = 0; reg < 4; ++reg) pref[reg] += acc[reg];
    if (t < 64) {
      ((float*)(stC + 1024))[t] = tailpref;   // fp32 tail (den-critical kpre!)
      tailpref += csum;
    }
    __syncthreads();                    // protect kT/vT/psK before re-staging
  }

  // inclusive group total (fp32, same [n][d1] layout)
  float* tp = totals + (size_t)blk * STATE;
  *(float4*)&tp[n * 32 + d1b] =
      make_float4(pref[0], pref[1], pref[2], pref[3]);
  if (t < 64) tp[1024 + t] = tailpref;
}

// ---------------------------------------------------------------------------
// Kernel 2: exclusive scan of group totals over the 16 groups per bh.
// grid = BH*STATE/256 = 68 blocks (exact).
// ---------------------------------------------------------------------------
__global__ __launch_bounds__(256) void totals_scan_kernel(float* __restrict__ totals) {
  int gidx = blockIdx.x * 256 + threadIdx.x;   // 0 .. BH*STATE-1
  int bh = gidx / STATE;
  int e  = gidx % STATE;
  float* base = totals + (size_t)(bh * NGROUP) * STATE + e;
  float a = 0.f;
#pragma unroll
  for (int g = 0; g < NGROUP; ++g) {
    float s = base[(size_t)g * STATE];
    base[(size_t)g * STATE] = a;
    a += s;
  }
}

// ---------------------------------------------------------------------------
// Kernel 3: MFMA output kernel.  grid = BH*NCHUNK, 256 threads (4 waves).
// ---------------------------------------------------------------------------
__global__ __launch_bounds__(256) void output_kernel(
    const float* __restrict__ q, const float* __restrict__ k,
    const float* __restrict__ v, const unsigned short* __restrict__ states,
    const float* __restrict__ totals, float* __restrict__ out) {
  int blk = blockIdx.x;
  int c   = blk & 127;
  int bh  = blk >> 7;
  int g   = c >> 3;                    // group index (GSIZE=8)
  size_t off = (size_t)blk * (C * D);
  const float4* qp4 = (const float4*)q + (size_t)blk * 512;
  const float4* kp4 = (const float4*)k + (size_t)blk * 512;
  const float4* vp4 = (const float4*)v + (size_t)blk * 512;
  const unsigned short* stc = states + (size_t)blk * STCH;
  const float* tb = totals + (size_t)(bh * NGROUP + g) * STATE;

  __shared__ __align__(16) unsigned short qbf[C * 40];    // [i][dd]
  __shared__ __align__(16) unsigned short kbf[C * 40];    // [j][dd]
  __shared__ __align__(16) unsigned short vTbf[D * 72];   // [n][j] permuted cols
  __shared__ __align__(16) unsigned short kvTbf[D * 40];  // [n][dd] permuted cols
  __shared__ __align__(16) unsigned short Tbf[C * 72];    // [i][j]
  __shared__ __align__(16) float q_s[C * 36];             // fp32 q rows
  __shared__ __align__(16) float kc_s[C * 36];            // fp32 k -> cumsum+kpre
  __shared__ __align__(16) float gtot[8 * 32];
  __shared__ __align__(16) float kpre_s[D], vpre_s[D], invdiv_s[C];

  int t  = threadIdx.x;
  int j0 = t >> 3;
  int cb = (t & 7) * 4;

  // ---- issue all global loads first ---------------------------------------
  float4 qA = qp4[t], qB = qp4[t + 256];
  float4 kA = kp4[t], kB = kp4[t + 256];
  float4 vA = vp4[t], vB = vp4[t + 256];
  uint2  su  = *(const uint2*)&stc[t * 4];     // 4 bf16 within-group KV prefix
  float4 tv4 = *(const float4*)&tb[t * 4];     // 4 fp32 group-prefix KV
  float4 tail = make_float4(0.f, 0.f, 0.f, 0.f);
  if (t < 16)
    tail = add4(*(const float4*)((const float*)(stc + 1024) + 4 * t),
                *(const float4*)&tb[1024 + 4 * t]);

  // zero Tbf while loads are in flight (masked region must read 0)
  for (int z = t; z < (C * 72) / 8; z += 256)
    ((uint4*)Tbf)[z] = make_uint4(0, 0, 0, 0);

  // ---- convert + stage ----------------------------------------------------
  *(float4*)&q_s[j0 * 36 + cb]         = qA;
  *(float4*)&q_s[(j0 + 32) * 36 + cb]  = qB;
  *(float4*)&kc_s[j0 * 36 + cb]        = kA;
  *(float4*)&kc_s[(j0 + 32) * 36 + cb] = kB;
  *(u16x4*)&qbf[j0 * 40 + cb] =
      (u16x4){f2bf(qA.x), f2bf(qA.y), f2bf(qA.z), f2bf(qA.w)};
  *(u16x4*)&qbf[(j0 + 32) * 40 + cb] =
      (u16x4){f2bf(qB.x), f2bf(qB.y), f2bf(qB.z), f2bf(qB.w)};
  *(u16x4*)&kbf[j0 * 40 + cb] =
      (u16x4){f2bf(kA.x), f2bf(kA.y), f2bf(kA.z), f2bf(kA.w)};
  *(u16x4*)&kbf[(j0 + 32) * 40 + cb] =
      (u16x4){f2bf(kB.x), f2bf(kB.y), f2bf(kB.z), f2bf(kB.w)};
  {
    const float* va = &vA.x; const float* vb = &vB.x;
#pragma unroll
    for (int cc = 0; cc < 4; ++cc) {
      int n = permcol(cb + cc);
      vTbf[n * 72 + j0]      = f2bf(va[cc]);
      vTbf[n * 72 + j0 + 32] = f2bf(vb[cc]);
    }
  }
  // KV prefix: bf16 state + fp32 group prefix -> bf16, direct layout copy
  {
    float s0 = bf2f((unsigned short)(su.x & 0xffff)) + tv4.x;
    float s1 = bf2f((unsigned short)(su.x >> 16))    + tv4.y;
    float s2 = bf2f((unsigned short)(su.y & 0xffff)) + tv4.z;
    float s3 = bf2f((unsigned short)(su.y >> 16))    + tv4.w;
    *(u16x4*)&kvTbf[(t >> 3) * 40 + (t & 7) * 4] =
        (u16x4){f2bf(s0), f2bf(s1), f2bf(s2), f2bf(s3)};
  }
  if (t < 8)            ((float4*)kpre_s)[t]     = tail;
  else if (t < 16)      ((float4*)vpre_s)[t - 8] = tail;
  __syncthreads();

  int lane = t & 63, w = t >> 6;
  int m16 = lane & 15, quad = lane >> 4;

  // ---- part 1: S tiles -> Tbf;  scan phase a ------------------------------
  const bf16x8 aQ = *(const bf16x8*)&qbf[(16 * w + m16) * 40 + quad * 8];
  for (int jb = 0; jb <= w; ++jb) {
    bf16x8 bK = *(const bf16x8*)&kbf[(16 * jb + m16) * 40 + quad * 8];
    f32x4 cS = {0.f, 0.f, 0.f, 0.f};
    cS = __builtin_amdgcn_mfma_f32_16x16x32_bf16(aQ, bK, cS, 0, 0, 0);
    int jcol = 16 * jb + m16;
#pragma unroll
    for (int reg = 0; reg < 4; ++reg) {
      int i = 16 * w + quad * 4 + reg;
      float tv = (jcol <= i) ? (1.f + cS[reg]) : 0.f;
      Tbf[i * 72 + jcol] = f2bf(tv);
    }
  }
  int rg = t >> 5;                     // row-group 0..7
  int e  = t & 31;
  float vals[8];
  {
    float run = 0.f;
#pragma unroll
    for (int r = 0; r < 8; ++r) {
      vals[r] = kc_s[(rg * 8 + r) * 36 + e];
      run += vals[r];
    }
    gtot[rg * 32 + e] = run;
  }
  __syncthreads();

  // ---- part 2: apply group offsets + kpre, write k-cumsum -----------------
  {
    float offv = kpre_s[e];
    for (int g2 = 0; g2 < rg; ++g2) offv += gtot[g2 * 32 + e];
    float cacc = offv;
#pragma unroll
    for (int r = 0; r < 8; ++r) {
      cacc += vals[r];
      kc_s[(rg * 8 + r) * 36 + e] = cacc;   // kpre + cumsum_local(k)
    }
  }
  __syncthreads();

  // ---- part 3: fp32 den (wave 0) + O MFMAs (all waves) --------------------
  if (t < 64) {
    int i = t;
    float dp = 0.f;
#pragma unroll
    for (int d4 = 0; d4 < 8; ++d4) {
      float4 qv = *(const float4*)&q_s[i * 36 + 4 * d4];
      float4 kc = *(const float4*)&kc_s[i * 36 + 4 * d4];
      dp += qv.x * kc.x + qv.y * kc.y + qv.z * kc.z + qv.w * kc.w;
    }
    invdiv_s[i] = 1.f / ((float)(c * C + i + 1) + dp);
  }
  f32x4 o0 = {0.f, 0.f, 0.f, 0.f}, o1 = {0.f, 0.f, 0.f, 0.f};
  {
    bf16x8 b0 = *(const bf16x8*)&kvTbf[(m16)      * 40 + quad * 8];
    bf16x8 b1 = *(const bf16x8*)&kvTbf[(16 + m16) * 40 + quad * 8];
    o0 = __builtin_amdgcn_mfma_f32_16x16x32_bf16(aQ, b0, o0, 0, 0, 0);
    o1 = __builtin_amdgcn_mfma_f32_16x16x32_bf16(aQ, b1, o1, 0, 0, 0);
  }
  int kbcnt = (w >= 2) ? 2 : 1;        // T zero past column 16w+15
  for (int kb2 = 0; kb2 < kbcnt; ++kb2) {
    bf16x8 aT = *(const bf16x8*)&Tbf[(16 * w + m16) * 72 + kb2 * 32 + quad * 8];
    bf16x8 b0 = *(const bf16x8*)&vTbf[(m16)      * 72 + kb2 * 32 + quad * 8];
    bf16x8 b1 = *(const bf16x8*)&vTbf[(16 + m16) * 72 + kb2 * 32 + quad * 8];
    o0 = __builtin_amdgcn_mfma_f32_16x16x32_bf16(aT, b0, o0, 0, 0, 0);
    o1 = __builtin_amdgcn_mfma_f32_16x16x32_bf16(aT, b1, o1, 0, 0, 0);
  }
  __syncthreads();

  // ---- epilogue: columns 2*m16, 2*m16+1 -> float2 stores ------------------
  int e0 = 2 * m16;
#pragma unroll
  for (int reg = 0; reg < 4; ++reg) {
    int i = 16 * w + quad * 4 + reg;
    float id = invdiv_s[i];
    float2 o;
    o.x = (vpre_s[e0]     + o0[reg]) * id;
    o.y = (vpre_s[e0 + 1] + o1[reg]) * id;
    *(float2*)&out[off + (size_t)i * D + e0] = o;
  }
}

// ---------------------------------------------------------------------------
extern "C" void kernel_launch(void* const* d_in, const int* in_sizes, int n_in,
                              void* d_out, int out_size, void* d_ws, size_t ws_size,
                              hipStream_t stream) {
  const float* q = (const float*)d_in[0];
  const float* k = (const float*)d_in[1];
  const float* v = (const float*)d_in[2];
  float* out = (float*)d_out;
  unsigned short* states = (unsigned short*)d_ws;             // 4.7 MB (bf16 KV + f32 tails)
  float* totals = (float*)(states + (size_t)NBLK * STCH);     // 1.1 MB fp32

  state_scan_kernel<<<BH * NGROUP, 256, 0, stream>>>(k, v, states, totals);
  totals_scan_kernel<<<(BH * STATE) / 256, 256, 0, stream>>>(totals);
  output_kernel<<<NBLK, 256, 0, stream>>>(q, k, v, states, totals, out);
}